// Round 14
// baseline (358.711 us; speedup 1.0000x reference)
//
#include <hip/hip_runtime.h>

// Darcy flow graph PDE residual — bucket-binned LDS aggregation, rev 8.
//
// Measured history: global float atomics ~17-20 G/s (R1/R2/R5); scattered-
// store write amplification fixed by LDS write-combining (R11); phase gather
// footprint fixed by bf16 packing (R13: phases < 79 us). R13 top: k_scatter
// 80 us, occupancy 36% (76.5 KB LDS -> 2 blocks/CU), flush ~12% lane util.
// Rev 8: SB 2048 (srec 32 KB -> 44 KB LDS -> 3 blocks/CU, 75% occ cap) and
// flush handles 8 buckets x 8 lanes per wave iteration (128 -> 16 iters).
//
// Edge record (8 B): w0 = src | dlo<<20 (dlo 10 bits); w1 = attr bits with
// LSB overwritten by comp (0=x,1=y); w1==0 => invalid edge.
//
// Binned ws layout (8E + 14N + 16KB ~= 78 MB < 80 MB proven):
//   [0, 8E)             ebuf : int2[E]
//   [8E, 8E+4N)         tpk  : uint[N]    packed bf16 {tmp0,tmp1}
//   [8E+4N, 8E+12N)     inv2 : float2[N]
//     (bhist = [8E, 8E+8.4MB) aliases tpk+inv2 — both dead until phase1)
//   [8E+12N, 8E+14N)    xpk  : ushort[N]  packed bf16 x
//   [8E+14N, +16KB)     counts[KMAX] | offsets[KMAX+1]
// Fallback (ws too small): proven R5 atomic path (1042 us).

typedef int   vi2 __attribute__((ext_vector_type(2)));
typedef int   vi4 __attribute__((ext_vector_type(4)));
typedef float vf4 __attribute__((ext_vector_type(4)));

#define K_BSH  10
#define BUCKET (1 << K_BSH)        // 1024 nodes per bucket
#define KMAX   1024

#define SB   2048                  // scatter/hist blocks
#define HT   512                   // hist threads
#define SB_T 512                   // scatter threads
#define SREC_CAP 4096              // LDS record stage per block (32 KB)
#define PT   512                   // phase block threads

static constexpr double PK  = 68719476736.0;   // 2^36
static constexpr double PKI = 1.0 / 68719476736.0;

__device__ __forceinline__ unsigned pack_bf16x2(float a, float b) {
    const unsigned ua = (__float_as_uint(a) + 0x8000u) >> 16;
    const unsigned ub = (__float_as_uint(b) + 0x8000u) & 0xFFFF0000u;
    return ua | ub;
}
__device__ __forceinline__ float bf_lo(unsigned p) {
    return __uint_as_float(p << 16);
}
__device__ __forceinline__ float bf_hi(unsigned p) {
    return __uint_as_float(p & 0xFFFF0000u);
}

// ---------------- binned path ----------------

__global__ __launch_bounds__(HT) void k_hist(
    const int* __restrict__ dstA, const float* __restrict__ x,
    int* __restrict__ bhist, unsigned short* __restrict__ xpk,
    int E, int K, int span, int N)
{
    __shared__ int lh[KMAX];
    for (int i = threadIdx.x; i < K; i += HT) lh[i] = 0;
    __syncthreads();
    const int beg = blockIdx.x * span;           // span % 4 == 0
    const int end = min(beg + span, E);          // E % 4 == 0
    for (int e = beg + (int)threadIdx.x * 4; e < end; e += HT * 4) {
        vi4 d = __builtin_nontemporal_load((const vi4*)&dstA[e]);
        atomicAdd(&lh[d.x >> K_BSH], 1);
        atomicAdd(&lh[d.y >> K_BSH], 1);
        atomicAdd(&lh[d.z >> K_BSH], 1);
        atomicAdd(&lh[d.w >> K_BSH], 1);
    }
    // pack x -> bf16 (grid-stride; independent of hist loop)
    for (int i = blockIdx.x * HT + threadIdx.x; i < N; i += SB * HT)
        xpk[i] = (unsigned short)((__float_as_uint(x[i]) + 0x8000u) >> 16);
    __syncthreads();
    int* row = bhist + (size_t)blockIdx.x * KMAX;
    for (int i = threadIdx.x; i < K; i += HT) row[i] = lh[i];
}

// One block per bucket k: exclusive prefix over the SB=2048 block rows
// (in place), total -> counts[k]. 64 threads x 32 rows each.
__global__ __launch_bounds__(64) void k_scanA(
    int* __restrict__ bhist, int* __restrict__ counts)
{
    const int k = blockIdx.x;
    const int t = threadIdx.x;                  // 0..63
    int v[32];
    int sum = 0;
    #pragma unroll
    for (int j = 0; j < 32; ++j) {
        v[j] = bhist[(size_t)(t * 32 + j) * KMAX + k];
        sum += v[j];
    }
    int incl = sum;
    #pragma unroll
    for (int d = 1; d < 64; d <<= 1) {
        int o = __shfl_up(incl, d, 64);
        if (t >= d) incl += o;
    }
    int excl = incl - sum;
    #pragma unroll
    for (int j = 0; j < 32; ++j) {
        const int tmp = v[j];
        bhist[(size_t)(t * 32 + j) * KMAX + k] = excl;
        excl += tmp;
    }
    if (t == 63) counts[k] = incl;
}

__global__ __launch_bounds__(KMAX) void k_scanB(
    const int* __restrict__ counts, int* __restrict__ offsets, int K)
{
    __shared__ int s[KMAX];
    const int t = threadIdx.x;
    const int v = (t < K) ? counts[t] : 0;
    s[t] = v;
    __syncthreads();
    for (int d = 1; d < KMAX; d <<= 1) {
        int add = (t >= d) ? s[t - d] : 0;
        __syncthreads();
        s[t] += add;
        __syncthreads();
    }
    if (t < K) {
        offsets[t] = s[t] - v;
        if (t == K - 1) offsets[K] = s[t];
    }
}

// LDS-staged scatter, single sweep: local histogram reconstructed from the
// scanned prefix table, records binned bucket-contiguous in LDS, flushed
// as dense per-bucket runs (full-line writes). Flush: 8 buckets x 8 lanes.
__global__ __launch_bounds__(SB_T) void k_scatter(
    const int* __restrict__ srcA, const int* __restrict__ dstA,
    const float* __restrict__ attr,
    const int* __restrict__ colbase,   // [SB][KMAX] excl prefixes (scanned)
    const int* __restrict__ counts,
    const int* __restrict__ offsets,
    int2* __restrict__ ebuf,
    int E, int K, int span)
{
    __shared__ int2 srec[SREC_CAP];            // 32 KB record stage
    __shared__ int  lpre[KMAX];
    __shared__ int  lcnt[KMAX];
    __shared__ int  lbase[KMAX];
    __shared__ int  wsum[8];

    const int tid  = threadIdx.x;
    const int lane = tid & 63;
    const int wid  = tid >> 6;                 // 8 waves
    const int b    = blockIdx.x;
    const bool last = (b == (int)gridDim.x - 1);
    const int* row  = colbase + (size_t)b * KMAX;
    const int* rowN = row + KMAX;

    for (int i = tid; i < KMAX; i += SB_T) {
        int h = 0, own = 0;
        if (i < K) {
            own = row[i];
            h   = (last ? counts[i] : rowN[i]) - own;
        }
        lpre[i]  = h;
        lcnt[i]  = 0;
        lbase[i] = (i < K ? offsets[i] : 0) + own;
    }
    __syncthreads();

    {
        const int a0 = lpre[2 * tid], a1 = lpre[2 * tid + 1];
        int psum = a0 + a1;
        int incl = psum;
        #pragma unroll
        for (int d = 1; d < 64; d <<= 1) {
            int o = __shfl_up(incl, d, 64);
            if (lane >= d) incl += o;
        }
        if (lane == 63) wsum[wid] = incl;
        __syncthreads();
        if (tid == 0) {
            int run = 0;
            #pragma unroll
            for (int w = 0; w < 8; ++w) { int t2 = wsum[w]; wsum[w] = run; run += t2; }
        }
        __syncthreads();
        const int excl = wsum[wid] + incl - psum;
        lpre[2 * tid]     = excl;
        lpre[2 * tid + 1] = excl + a0;
    }
    __syncthreads();

    const int beg = b * span;
    const int end = min(beg + span, E);

    for (int e = beg + tid * 4; e < end; e += SB_T * 4) {
        vi4 s4 = __builtin_nontemporal_load((const vi4*)&srcA[e]);
        vi4 d4 = __builtin_nontemporal_load((const vi4*)&dstA[e]);
        vf4 a0 = __builtin_nontemporal_load((const vf4*)&attr[2 * e]);
        vf4 a1 = __builtin_nontemporal_load((const vf4*)&attr[2 * e + 4]);

        #define PLACE(SRC, DST, AX, AY)                                        \
        {                                                                      \
            const int k    = (DST) >> K_BSH;                                   \
            const int r    = atomicAdd(&lcnt[k], 1);                           \
            const int slot = lpre[k] + r;                                      \
            const int comp = ((AX) != 0.0f) ? 0 : 1;                           \
            const float av = comp ? (AY) : (AX);                               \
            unsigned enc = 0u;                                                 \
            if ((AX) != 0.0f || (AY) != 0.0f)                                  \
                enc = (__float_as_uint(av) & ~1u) | (unsigned)comp;            \
            const int w0 = (SRC) | (((DST) & (BUCKET - 1)) << 20);             \
            srec[slot] = make_int2(w0, (int)enc);                              \
        }
        PLACE(s4.x, d4.x, a0.x, a0.y)
        PLACE(s4.y, d4.y, a0.z, a0.w)
        PLACE(s4.z, d4.z, a1.x, a1.y)
        PLACE(s4.w, d4.w, a1.z, a1.w)
        #undef PLACE
    }
    __syncthreads();

    // flush: wave w owns 128 buckets; 8 buckets x 8 lanes per iteration
    const int kbeg = wid * (KMAX / 8);
    const int sub  = lane & 7;
    const int koff = lane >> 3;                // 0..7
    for (int k0 = kbeg; k0 < kbeg + (KMAX / 8); k0 += 8) {
        const int k   = k0 + koff;
        const int cnt = lcnt[k];
        const int lp  = lpre[k];
        const int gb  = lbase[k];
        for (int i = sub; i < cnt; i += 8)
            ebuf[gb + i] = srec[lp + i];
    }
}

__global__ __launch_bounds__(PT) void k_phase1(
    const int2* __restrict__ ebuf, const int* __restrict__ offsets,
    const unsigned short* __restrict__ xpk,     // bf16 x (src gathers, 2 MB)
    const float* __restrict__ x,                // full x (dst preload)
    const float* __restrict__ a_x,
    unsigned* __restrict__ tpk,                 // out: packed bf16 {tmp0,tmp1}
    float2* __restrict__ inv2, int N)
{
    __shared__ double pk0[BUCKET], pk1[BUCKET];   // sum + 2^36*cnt packed
    __shared__ float xl[BUCKET];
    const int k  = blockIdx.x;
    const int lo = k << K_BSH;
    for (int i = threadIdx.x; i < BUCKET; i += PT) {
        pk0[i] = 0.0; pk1[i] = 0.0;
        const int node = lo + i;
        xl[i] = (node < N) ? x[node] : 0.0f;
    }
    __syncthreads();
    const int beg = offsets[k], end = offsets[k + 1];
    const int start = beg & ~1;                   // 16B-aligned vi4 loads

    #define P1REC(W0, W1)                                                      \
    {                                                                          \
        const unsigned enc = (unsigned)(W1);                                   \
        if (enc != 0u) {                                                       \
            const int src  = (W0) & 0xFFFFF;                                   \
            const int dlo  = ((unsigned)(W0)) >> 20;                           \
            const float a  = __uint_as_float(enc);                             \
            const float xs = __uint_as_float((unsigned)xpk[src] << 16);        \
            const float msg = (xs - xl[dlo]) / a;                              \
            double* p = (enc & 1) ? pk1 : pk0;                                 \
            atomicAdd(&p[dlo], (double)msg + PK);                              \
        }                                                                      \
    }
    for (int i = start + (int)threadIdx.x * 4; i < end; i += PT * 4) {
        vi4 r0 = __builtin_nontemporal_load((const vi4*)(ebuf + i));
        if (i + 2 < end) {
            vi4 r1 = __builtin_nontemporal_load((const vi4*)(ebuf + i + 2));
            if (i >= beg)    P1REC(r0.x, r0.y)
            if (i + 1 < end) P1REC(r0.z, r0.w)
            P1REC(r1.x, r1.y)
            if (i + 3 < end) P1REC(r1.z, r1.w)
        } else {
            if (i >= beg)    P1REC(r0.x, r0.y)
            if (i + 1 < end) P1REC(r0.z, r0.w)
        }
    }
    #undef P1REC

    __syncthreads();
    for (int i = threadIdx.x; i < BUCKET; i += PT) {
        const int node = lo + i;
        if (node >= N) break;
        const double p0 = pk0[i], p1 = pk1[i];
        const double c0 = rint(p0 * PKI);
        const double c1 = rint(p1 * PKI);
        const float  s0 = (float)(p0 - c0 * PK);
        const float  s1 = (float)(p1 - c1 * PK);
        const float  i0 = 1.0f / (float)fmax(c0, 1.0);
        const float  i1 = 1.0f / (float)fmax(c1, 1.0);
        const float  a  = a_x[node];
        tpk[node] = pack_bf16x2(a * s0 * i0, a * s1 * i1);
        float2 v; v.x = i0; v.y = i1;
        inv2[node] = v;
    }
}

__global__ __launch_bounds__(PT) void k_phase2(
    const int2* __restrict__ ebuf, const int* __restrict__ offsets,
    const unsigned* __restrict__ tpk,           // packed bf16 {tmp0,tmp1}, 4 MB
    const float2* __restrict__ inv2,
    const int* __restrict__ mask,
    float* __restrict__ out, int N)
{
    __shared__ float acc[BUCKET];
    __shared__ float2 tl[BUCKET], il[BUCKET];
    const int k  = blockIdx.x;
    const int lo = k << K_BSH;
    for (int i = threadIdx.x; i < BUCKET; i += PT) {
        acc[i] = 0.0f;
        const int node = lo + i;
        if (node < N) {
            const unsigned p = tpk[node];
            tl[i] = make_float2(bf_lo(p), bf_hi(p));
            il[i] = inv2[node];
        } else {
            tl[i] = make_float2(0.f, 0.f); il[i] = make_float2(0.f, 0.f);
        }
    }
    __syncthreads();
    const int beg = offsets[k], end = offsets[k + 1];
    const int start = beg & ~1;

    #define P2REC(W0, W1)                                                      \
    {                                                                          \
        const unsigned enc = (unsigned)(W1);                                   \
        if (enc != 0u) {                                                       \
            const int src  = (W0) & 0xFFFFF;                                   \
            const int dlo  = ((unsigned)(W0)) >> 20;                           \
            const int comp = enc & 1;                                          \
            const float a  = __uint_as_float(enc);                             \
            const unsigned ps = tpk[src];                                      \
            const float2 td = tl[dlo];                                         \
            const float2 ic = il[dlo];                                         \
            const float tsv = comp ? bf_hi(ps) : bf_lo(ps);                    \
            const float tdv = comp ? td.y : td.x;                              \
            const float icv = comp ? ic.y : ic.x;                              \
            atomicAdd(&acc[dlo], (tsv - tdv) / a * icv);                       \
        }                                                                      \
    }
    for (int i = start + (int)threadIdx.x * 4; i < end; i += PT * 4) {
        vi4 r0 = __builtin_nontemporal_load((const vi4*)(ebuf + i));
        if (i + 2 < end) {
            vi4 r1 = __builtin_nontemporal_load((const vi4*)(ebuf + i + 2));
            if (i >= beg)    P2REC(r0.x, r0.y)
            if (i + 1 < end) P2REC(r0.z, r0.w)
            P2REC(r1.x, r1.y)
            if (i + 3 < end) P2REC(r1.z, r1.w)
        } else {
            if (i >= beg)    P2REC(r0.x, r0.y)
            if (i + 1 < end) P2REC(r0.z, r0.w)
        }
    }
    #undef P2REC

    __syncthreads();
    for (int i = threadIdx.x; i < BUCKET; i += PT) {
        const int node = lo + i;
        if (node >= N) break;
        out[node] = (acc[i] + 1.0f) * (1.0f - (float)mask[node]);
    }
}

// ---------------- fallback path (proven R5, 1042 us) ----------------

#define BLK   256
#define EPT   4
#define CHUNK (BLK * EPT)
#define GRAB  8

__device__ __forceinline__ int xcd_id() {
    return __builtin_amdgcn_s_getreg((31u << 11) | 20) & 7;
}
__device__ __forceinline__ void wg_add_d(double* p, double v) {
    __hip_atomic_fetch_add(p, v, __ATOMIC_RELAXED, __HIP_MEMORY_SCOPE_WORKGROUP);
}
__device__ __forceinline__ void wg_add_f(float* p, float v) {
    __hip_atomic_fetch_add(p, v, __ATOMIC_RELAXED, __HIP_MEMORY_SCOPE_WORKGROUP);
}

__global__ __launch_bounds__(BLK) void edge_pass1(
    const int* __restrict__ srcA, const int* __restrict__ dstA,
    const float* __restrict__ attr, const float* __restrict__ x,
    double2* __restrict__ pk, int* __restrict__ tickets,
    int E, int nchunk, int sliceSz, int N)
{
    const int xcc = xcd_id();
    const int lo  = xcc * sliceSz;
    const int w   = min(sliceSz, N - lo);
    __shared__ int s_q;
    for (;;) {
        if (threadIdx.x == 0) s_q = atomicAdd(&tickets[xcc], 1);
        __syncthreads();
        const int q = s_q;
        __syncthreads();
        if (q * GRAB >= nchunk) break;
        for (int cc = 0; cc < GRAB; ++cc) {
            const int c = q * GRAB + cc;
            if (c >= nchunk) break;
            const int base = c * CHUNK + threadIdx.x * EPT;
            if (base >= E) continue;
            vi4 sv  = __builtin_nontemporal_load((const vi4*)&srcA[base]);
            vi4 dv  = __builtin_nontemporal_load((const vi4*)&dstA[base]);
            vf4 a01 = __builtin_nontemporal_load((const vf4*)&attr[2 * base]);
            vf4 a23 = __builtin_nontemporal_load((const vf4*)&attr[2 * base + 4]);
            #define P1(S, D, AX, AY)                                                  \
                if ((unsigned)((D) - lo) < (unsigned)w) {                             \
                    float diff = x[S] - x[D];                                         \
                    if ((AX) != 0.0f) wg_add_d(&pk[D].x, (double)(diff/(AX)) + PK);   \
                    if ((AY) != 0.0f) wg_add_d(&pk[D].y, (double)(diff/(AY)) + PK);   \
                }
            P1(sv.x, dv.x, a01.x, a01.y)
            P1(sv.y, dv.y, a01.z, a01.w)
            P1(sv.z, dv.z, a23.x, a23.y)
            P1(sv.w, dv.w, a23.z, a23.w)
            #undef P1
        }
    }
}

__global__ __launch_bounds__(BLK) void node_mid(
    double2* __restrict__ pk, const float* __restrict__ a_x, int N)
{
    float4* f4 = (float4*)pk;
    for (int i = blockIdx.x * BLK + threadIdx.x; i < N; i += gridDim.x * BLK) {
        double2 p = pk[i];
        double c0 = rint(p.x * PKI);
        double c1 = rint(p.y * PKI);
        float  s0 = (float)(p.x - c0 * PK);
        float  s1 = (float)(p.y - c1 * PK);
        float  i0 = 1.0f / (float)fmax(c0, 1.0);
        float  i1 = 1.0f / (float)fmax(c1, 1.0);
        float  a  = a_x[i];
        f4[i] = make_float4(a * s0 * i0, a * s1 * i1, i0, i1);
    }
}

__global__ __launch_bounds__(BLK) void edge_pass2(
    const int* __restrict__ srcA, const int* __restrict__ dstA,
    const float* __restrict__ attr, const float4* __restrict__ tf,
    float* __restrict__ acc2, int* __restrict__ tickets,
    int E, int nchunk, int sliceSz, int N)
{
    const int xcc = xcd_id();
    const int lo  = xcc * sliceSz;
    const int w   = min(sliceSz, N - lo);
    __shared__ int s_q;
    for (;;) {
        if (threadIdx.x == 0) s_q = atomicAdd(&tickets[8 + xcc], 1);
        __syncthreads();
        const int q = s_q;
        __syncthreads();
        if (q * GRAB >= nchunk) break;
        for (int cc = 0; cc < GRAB; ++cc) {
            const int c = q * GRAB + cc;
            if (c >= nchunk) break;
            const int base = c * CHUNK + threadIdx.x * EPT;
            if (base >= E) continue;
            vi4 sv  = __builtin_nontemporal_load((const vi4*)&srcA[base]);
            vi4 dv  = __builtin_nontemporal_load((const vi4*)&dstA[base]);
            vf4 a01 = __builtin_nontemporal_load((const vf4*)&attr[2 * base]);
            vf4 a23 = __builtin_nontemporal_load((const vf4*)&attr[2 * base + 4]);
            #define P2(S, D, AX, AY)                                                  \
                if ((unsigned)((D) - lo) < (unsigned)w) {                             \
                    float4 ts = tf[S], td = tf[D];                                    \
                    float contrib = 0.0f; bool any = false;                           \
                    if ((AX) != 0.0f) { contrib += (ts.x - td.x) / (AX) * td.z; any = true; } \
                    if ((AY) != 0.0f) { contrib += (ts.y - td.y) / (AY) * td.w; any = true; } \
                    if (any) wg_add_f(&acc2[D], contrib);                             \
                }
            P2(sv.x, dv.x, a01.x, a01.y)
            P2(sv.y, dv.y, a01.z, a01.w)
            P2(sv.z, dv.z, a23.x, a23.y)
            P2(sv.w, dv.w, a23.z, a23.w)
            #undef P2
        }
    }
}

__global__ __launch_bounds__(BLK) void node_out(
    const float* __restrict__ acc2, const int* __restrict__ mask,
    float* __restrict__ out, int N)
{
    for (int i = blockIdx.x * BLK + threadIdx.x; i < N; i += gridDim.x * BLK)
        out[i] = (acc2[i] + 1.0f) * (1.0f - (float)mask[i]);
}

// ---------------- launcher ----------------

extern "C" void kernel_launch(void* const* d_in, const int* in_sizes, int n_in,
                              void* d_out, int out_size, void* d_ws, size_t ws_size,
                              hipStream_t stream)
{
    const float* x    = (const float*)d_in[0];
    const float* a_x  = (const float*)d_in[1];
    const int*   eidx = (const int*)d_in[2];
    const float* attr = (const float*)d_in[3];
    const int*   mask = (const int*)d_in[4];
    float* out = (float*)d_out;

    const int N = in_sizes[0];
    const int E = in_sizes[2] / 2;
    const int K = (N + BUCKET - 1) >> K_BSH;

    const size_t need = (size_t)E * 8 + (size_t)N * 14 + 16384;
    const size_t bhist_bytes = (size_t)SB * KMAX * 4;   // 8 MB
    const int span = (((E + SB - 1) / SB) + 3) & ~3;

    if (ws_size >= need && N <= (1 << 20) && K <= KMAX &&
        bhist_bytes <= (size_t)N * 12 && span <= SREC_CAP) {
        char* p = (char*)d_ws;
        int2*     ebuf    = (int2*)p;
        unsigned* tpk     = (unsigned*)(p + (size_t)E * 8);
        float2*   inv2    = (float2*)(p + (size_t)E * 8 + (size_t)N * 4);
        unsigned short* xpk = (unsigned short*)(p + (size_t)E * 8 + (size_t)N * 12);
        int*      counts  = (int*)(p + (size_t)E * 8 + (size_t)N * 14);
        int*      offsets = counts + KMAX;        // K+1 slots
        int*      bhist   = (int*)tpk;            // alias tpk+inv2 (12N >= 8MB)

        const int* srcA = eidx;
        const int* dstA = eidx + E;

        k_hist<<<SB, HT, 0, stream>>>(dstA, x, bhist, xpk, E, K, span, N);
        k_scanA<<<K, 64, 0, stream>>>(bhist, counts);
        k_scanB<<<1, KMAX, 0, stream>>>(counts, offsets, K);
        k_scatter<<<SB, SB_T, 0, stream>>>(srcA, dstA, attr, bhist, counts,
                                           offsets, ebuf, E, K, span);
        k_phase1<<<K, PT, 0, stream>>>(ebuf, offsets, xpk, x, a_x, tpk, inv2, N);
        k_phase2<<<K, PT, 0, stream>>>(ebuf, offsets, tpk, inv2, mask, out, N);
    } else {
        // proven R5 fallback (20N+64 bytes of ws)
        char* ws = (char*)d_ws;
        double2* pk      = (double2*)(ws);
        float*   acc2    = (float*)(ws + (size_t)16 * N);
        int*     tickets = (int*)(ws + (size_t)20 * N);

        hipMemsetAsync(d_ws, 0, (size_t)20 * N + 64, stream);

        const int sliceSz = (N + 7) / 8;
        const int nchunk  = (E + CHUNK - 1) / CHUNK;
        const int EGRID   = 2048;
        int ngrid = (N + BLK - 1) / BLK;
        const int NGRID   = ngrid < 2048 ? ngrid : 2048;

        edge_pass1<<<EGRID, BLK, 0, stream>>>(
            eidx, eidx + E, attr, x, pk, tickets, E, nchunk, sliceSz, N);
        node_mid<<<NGRID, BLK, 0, stream>>>(pk, a_x, N);
        edge_pass2<<<EGRID, BLK, 0, stream>>>(
            eidx, eidx + E, attr, (const float4*)pk, acc2, tickets,
            E, nchunk, sliceSz, N);
        node_out<<<NGRID, BLK, 0, stream>>>(acc2, mask, out, N);
    }
}

// Round 15
// 314.812 us; speedup vs baseline: 1.1394x; 1.1394x over previous
//
#include <hip/hip_runtime.h>

// Darcy flow graph PDE residual — bucket-binned LDS aggregation, rev 9.
//
// Measured history: global float atomics ~17-20 G/s (R1/R2/R5); scattered-
// store write amplification fixed by LDS write-combining (R11); phase gather
// footprint fixed by bf16 packing (R13). R14 lesson: SB=2048 made scatter
// faster (67 us) but taxed hist/scanA/write-amp for a net +25 us — SB
// couples four kernels. Rev 9 = R13 config (SB=1024, 333 us proven) plus the
// one decoupled win from R14: flush with 8 buckets x 8 lanes per wave
// iteration (lane util ~12% -> ~95%, run contiguity preserved).
//
// Edge record (8 B): w0 = src | dlo<<20 (dlo 10 bits); w1 = attr bits with
// LSB overwritten by comp (0=x,1=y); w1==0 => invalid edge.
//
// Binned ws layout (8E + 14N + 16KB ~= 78 MB < 80 MB proven):
//   [0, 8E)             ebuf : int2[E]
//   [8E, 8E+4N)         tpk  : uint[N]    packed bf16 {tmp0,tmp1}
//   [8E+4N, 8E+12N)     inv2 : float2[N]
//     (bhist = [8E, 8E+4MB) aliases tpk — dead until phase1)
//   [8E+12N, 8E+14N)    xpk  : ushort[N]  packed bf16 x
//   [8E+14N, +16KB)     counts[KMAX] | offsets[KMAX+1]
// Fallback (ws too small): proven R5 atomic path (1042 us).

typedef int   vi2 __attribute__((ext_vector_type(2)));
typedef int   vi4 __attribute__((ext_vector_type(4)));
typedef float vf4 __attribute__((ext_vector_type(4)));

#define K_BSH  10
#define BUCKET (1 << K_BSH)        // 1024 nodes per bucket
#define KMAX   1024

#define SB   1024                  // scatter/hist blocks (R13 proven)
#define HT   512                   // hist threads
#define SB_T 512                   // scatter threads
#define SREC_CAP 8192              // LDS record stage per block (64 KB)
#define PT   512                   // phase block threads

static constexpr double PK  = 68719476736.0;   // 2^36
static constexpr double PKI = 1.0 / 68719476736.0;

__device__ __forceinline__ unsigned pack_bf16x2(float a, float b) {
    const unsigned ua = (__float_as_uint(a) + 0x8000u) >> 16;
    const unsigned ub = (__float_as_uint(b) + 0x8000u) & 0xFFFF0000u;
    return ua | ub;
}
__device__ __forceinline__ float bf_lo(unsigned p) {
    return __uint_as_float(p << 16);
}
__device__ __forceinline__ float bf_hi(unsigned p) {
    return __uint_as_float(p & 0xFFFF0000u);
}

// ---------------- binned path ----------------

__global__ __launch_bounds__(HT) void k_hist(
    const int* __restrict__ dstA, const float* __restrict__ x,
    int* __restrict__ bhist, unsigned short* __restrict__ xpk,
    int E, int K, int span, int N)
{
    __shared__ int lh[KMAX];
    for (int i = threadIdx.x; i < K; i += HT) lh[i] = 0;
    __syncthreads();
    const int beg = blockIdx.x * span;           // span % 4 == 0
    const int end = min(beg + span, E);          // E % 4 == 0
    for (int e = beg + (int)threadIdx.x * 4; e < end; e += HT * 4) {
        vi4 d = __builtin_nontemporal_load((const vi4*)&dstA[e]);
        atomicAdd(&lh[d.x >> K_BSH], 1);
        atomicAdd(&lh[d.y >> K_BSH], 1);
        atomicAdd(&lh[d.z >> K_BSH], 1);
        atomicAdd(&lh[d.w >> K_BSH], 1);
    }
    // pack x -> bf16 (grid-stride; independent of hist loop)
    for (int i = blockIdx.x * HT + threadIdx.x; i < N; i += SB * HT)
        xpk[i] = (unsigned short)((__float_as_uint(x[i]) + 0x8000u) >> 16);
    __syncthreads();
    int* row = bhist + (size_t)blockIdx.x * KMAX;
    for (int i = threadIdx.x; i < K; i += HT) row[i] = lh[i];
}

// One block per bucket k: exclusive prefix over the SB=1024 block rows
// (in place), total -> counts[k]. 64 threads x 16 rows each.
__global__ __launch_bounds__(64) void k_scanA(
    int* __restrict__ bhist, int* __restrict__ counts)
{
    const int k = blockIdx.x;
    const int t = threadIdx.x;                  // 0..63
    int v[16];
    int sum = 0;
    #pragma unroll
    for (int j = 0; j < 16; ++j) {
        v[j] = bhist[(size_t)(t * 16 + j) * KMAX + k];
        sum += v[j];
    }
    int incl = sum;
    #pragma unroll
    for (int d = 1; d < 64; d <<= 1) {
        int o = __shfl_up(incl, d, 64);
        if (t >= d) incl += o;
    }
    int excl = incl - sum;
    #pragma unroll
    for (int j = 0; j < 16; ++j) {
        const int tmp = v[j];
        bhist[(size_t)(t * 16 + j) * KMAX + k] = excl;
        excl += tmp;
    }
    if (t == 63) counts[k] = incl;
}

__global__ __launch_bounds__(KMAX) void k_scanB(
    const int* __restrict__ counts, int* __restrict__ offsets, int K)
{
    __shared__ int s[KMAX];
    const int t = threadIdx.x;
    const int v = (t < K) ? counts[t] : 0;
    s[t] = v;
    __syncthreads();
    for (int d = 1; d < KMAX; d <<= 1) {
        int add = (t >= d) ? s[t - d] : 0;
        __syncthreads();
        s[t] += add;
        __syncthreads();
    }
    if (t < K) {
        offsets[t] = s[t] - v;
        if (t == K - 1) offsets[K] = s[t];
    }
}

// LDS-staged scatter, single sweep: local histogram reconstructed from the
// scanned prefix table, records binned bucket-contiguous in LDS, flushed
// as dense per-bucket runs (full-line writes). Flush: 8 buckets x 8 lanes.
__global__ __launch_bounds__(SB_T) void k_scatter(
    const int* __restrict__ srcA, const int* __restrict__ dstA,
    const float* __restrict__ attr,
    const int* __restrict__ colbase,   // [SB][KMAX] excl prefixes (scanned)
    const int* __restrict__ counts,
    const int* __restrict__ offsets,
    int2* __restrict__ ebuf,
    int E, int K, int span)
{
    __shared__ int2 srec[SREC_CAP];            // 64 KB record stage
    __shared__ int  lpre[KMAX];
    __shared__ int  lcnt[KMAX];
    __shared__ int  lbase[KMAX];
    __shared__ int  wsum[8];

    const int tid  = threadIdx.x;
    const int lane = tid & 63;
    const int wid  = tid >> 6;                 // 8 waves
    const int b    = blockIdx.x;
    const bool last = (b == (int)gridDim.x - 1);
    const int* row  = colbase + (size_t)b * KMAX;
    const int* rowN = row + KMAX;

    for (int i = tid; i < KMAX; i += SB_T) {
        int h = 0, own = 0;
        if (i < K) {
            own = row[i];
            h   = (last ? counts[i] : rowN[i]) - own;
        }
        lpre[i]  = h;
        lcnt[i]  = 0;
        lbase[i] = (i < K ? offsets[i] : 0) + own;
    }
    __syncthreads();

    {
        const int a0 = lpre[2 * tid], a1 = lpre[2 * tid + 1];
        int psum = a0 + a1;
        int incl = psum;
        #pragma unroll
        for (int d = 1; d < 64; d <<= 1) {
            int o = __shfl_up(incl, d, 64);
            if (lane >= d) incl += o;
        }
        if (lane == 63) wsum[wid] = incl;
        __syncthreads();
        if (tid == 0) {
            int run = 0;
            #pragma unroll
            for (int w = 0; w < 8; ++w) { int t2 = wsum[w]; wsum[w] = run; run += t2; }
        }
        __syncthreads();
        const int excl = wsum[wid] + incl - psum;
        lpre[2 * tid]     = excl;
        lpre[2 * tid + 1] = excl + a0;
    }
    __syncthreads();

    const int beg = b * span;
    const int end = min(beg + span, E);

    for (int e = beg + tid * 4; e < end; e += SB_T * 4) {
        vi4 s4 = __builtin_nontemporal_load((const vi4*)&srcA[e]);
        vi4 d4 = __builtin_nontemporal_load((const vi4*)&dstA[e]);
        vf4 a0 = __builtin_nontemporal_load((const vf4*)&attr[2 * e]);
        vf4 a1 = __builtin_nontemporal_load((const vf4*)&attr[2 * e + 4]);

        #define PLACE(SRC, DST, AX, AY)                                        \
        {                                                                      \
            const int k    = (DST) >> K_BSH;                                   \
            const int r    = atomicAdd(&lcnt[k], 1);                           \
            const int slot = lpre[k] + r;                                      \
            const int comp = ((AX) != 0.0f) ? 0 : 1;                           \
            const float av = comp ? (AY) : (AX);                               \
            unsigned enc = 0u;                                                 \
            if ((AX) != 0.0f || (AY) != 0.0f)                                  \
                enc = (__float_as_uint(av) & ~1u) | (unsigned)comp;            \
            const int w0 = (SRC) | (((DST) & (BUCKET - 1)) << 20);             \
            srec[slot] = make_int2(w0, (int)enc);                              \
        }
        PLACE(s4.x, d4.x, a0.x, a0.y)
        PLACE(s4.y, d4.y, a0.z, a0.w)
        PLACE(s4.z, d4.z, a1.x, a1.y)
        PLACE(s4.w, d4.w, a1.z, a1.w)
        #undef PLACE
    }
    __syncthreads();

    // flush: wave w owns 128 buckets; 8 buckets x 8 lanes per iteration
    const int kbeg = wid * (KMAX / 8);
    const int sub  = lane & 7;
    const int koff = lane >> 3;                // 0..7
    for (int k0 = kbeg; k0 < kbeg + (KMAX / 8); k0 += 8) {
        const int k   = k0 + koff;
        const int cnt = lcnt[k];
        const int lp  = lpre[k];
        const int gb  = lbase[k];
        for (int i = sub; i < cnt; i += 8)
            ebuf[gb + i] = srec[lp + i];
    }
}

__global__ __launch_bounds__(PT) void k_phase1(
    const int2* __restrict__ ebuf, const int* __restrict__ offsets,
    const unsigned short* __restrict__ xpk,     // bf16 x (src gathers, 2 MB)
    const float* __restrict__ x,                // full x (dst preload)
    const float* __restrict__ a_x,
    unsigned* __restrict__ tpk,                 // out: packed bf16 {tmp0,tmp1}
    float2* __restrict__ inv2, int N)
{
    __shared__ double pk0[BUCKET], pk1[BUCKET];   // sum + 2^36*cnt packed
    __shared__ float xl[BUCKET];
    const int k  = blockIdx.x;
    const int lo = k << K_BSH;
    for (int i = threadIdx.x; i < BUCKET; i += PT) {
        pk0[i] = 0.0; pk1[i] = 0.0;
        const int node = lo + i;
        xl[i] = (node < N) ? x[node] : 0.0f;
    }
    __syncthreads();
    const int beg = offsets[k], end = offsets[k + 1];
    const int start = beg & ~1;                   // 16B-aligned vi4 loads

    #define P1REC(W0, W1)                                                      \
    {                                                                          \
        const unsigned enc = (unsigned)(W1);                                   \
        if (enc != 0u) {                                                       \
            const int src  = (W0) & 0xFFFFF;                                   \
            const int dlo  = ((unsigned)(W0)) >> 20;                           \
            const float a  = __uint_as_float(enc);                             \
            const float xs = __uint_as_float((unsigned)xpk[src] << 16);        \
            const float msg = (xs - xl[dlo]) / a;                              \
            double* p = (enc & 1) ? pk1 : pk0;                                 \
            atomicAdd(&p[dlo], (double)msg + PK);                              \
        }                                                                      \
    }
    for (int i = start + (int)threadIdx.x * 4; i < end; i += PT * 4) {
        vi4 r0 = __builtin_nontemporal_load((const vi4*)(ebuf + i));
        if (i + 2 < end) {
            vi4 r1 = __builtin_nontemporal_load((const vi4*)(ebuf + i + 2));
            if (i >= beg)    P1REC(r0.x, r0.y)
            if (i + 1 < end) P1REC(r0.z, r0.w)
            P1REC(r1.x, r1.y)
            if (i + 3 < end) P1REC(r1.z, r1.w)
        } else {
            if (i >= beg)    P1REC(r0.x, r0.y)
            if (i + 1 < end) P1REC(r0.z, r0.w)
        }
    }
    #undef P1REC

    __syncthreads();
    for (int i = threadIdx.x; i < BUCKET; i += PT) {
        const int node = lo + i;
        if (node >= N) break;
        const double p0 = pk0[i], p1 = pk1[i];
        const double c0 = rint(p0 * PKI);
        const double c1 = rint(p1 * PKI);
        const float  s0 = (float)(p0 - c0 * PK);
        const float  s1 = (float)(p1 - c1 * PK);
        const float  i0 = 1.0f / (float)fmax(c0, 1.0);
        const float  i1 = 1.0f / (float)fmax(c1, 1.0);
        const float  a  = a_x[node];
        tpk[node] = pack_bf16x2(a * s0 * i0, a * s1 * i1);
        float2 v; v.x = i0; v.y = i1;
        inv2[node] = v;
    }
}

__global__ __launch_bounds__(PT) void k_phase2(
    const int2* __restrict__ ebuf, const int* __restrict__ offsets,
    const unsigned* __restrict__ tpk,           // packed bf16 {tmp0,tmp1}, 4 MB
    const float2* __restrict__ inv2,
    const int* __restrict__ mask,
    float* __restrict__ out, int N)
{
    __shared__ float acc[BUCKET];
    __shared__ float2 tl[BUCKET], il[BUCKET];
    const int k  = blockIdx.x;
    const int lo = k << K_BSH;
    for (int i = threadIdx.x; i < BUCKET; i += PT) {
        acc[i] = 0.0f;
        const int node = lo + i;
        if (node < N) {
            const unsigned p = tpk[node];
            tl[i] = make_float2(bf_lo(p), bf_hi(p));
            il[i] = inv2[node];
        } else {
            tl[i] = make_float2(0.f, 0.f); il[i] = make_float2(0.f, 0.f);
        }
    }
    __syncthreads();
    const int beg = offsets[k], end = offsets[k + 1];
    const int start = beg & ~1;

    #define P2REC(W0, W1)                                                      \
    {                                                                          \
        const unsigned enc = (unsigned)(W1);                                   \
        if (enc != 0u) {                                                       \
            const int src  = (W0) & 0xFFFFF;                                   \
            const int dlo  = ((unsigned)(W0)) >> 20;                           \
            const int comp = enc & 1;                                          \
            const float a  = __uint_as_float(enc);                             \
            const unsigned ps = tpk[src];                                      \
            const float2 td = tl[dlo];                                         \
            const float2 ic = il[dlo];                                         \
            const float tsv = comp ? bf_hi(ps) : bf_lo(ps);                    \
            const float tdv = comp ? td.y : td.x;                              \
            const float icv = comp ? ic.y : ic.x;                              \
            atomicAdd(&acc[dlo], (tsv - tdv) / a * icv);                       \
        }                                                                      \
    }
    for (int i = start + (int)threadIdx.x * 4; i < end; i += PT * 4) {
        vi4 r0 = __builtin_nontemporal_load((const vi4*)(ebuf + i));
        if (i + 2 < end) {
            vi4 r1 = __builtin_nontemporal_load((const vi4*)(ebuf + i + 2));
            if (i >= beg)    P2REC(r0.x, r0.y)
            if (i + 1 < end) P2REC(r0.z, r0.w)
            P2REC(r1.x, r1.y)
            if (i + 3 < end) P2REC(r1.z, r1.w)
        } else {
            if (i >= beg)    P2REC(r0.x, r0.y)
            if (i + 1 < end) P2REC(r0.z, r0.w)
        }
    }
    #undef P2REC

    __syncthreads();
    for (int i = threadIdx.x; i < BUCKET; i += PT) {
        const int node = lo + i;
        if (node >= N) break;
        out[node] = (acc[i] + 1.0f) * (1.0f - (float)mask[node]);
    }
}

// ---------------- fallback path (proven R5, 1042 us) ----------------

#define BLK   256
#define EPT   4
#define CHUNK (BLK * EPT)
#define GRAB  8

__device__ __forceinline__ int xcd_id() {
    return __builtin_amdgcn_s_getreg((31u << 11) | 20) & 7;
}
__device__ __forceinline__ void wg_add_d(double* p, double v) {
    __hip_atomic_fetch_add(p, v, __ATOMIC_RELAXED, __HIP_MEMORY_SCOPE_WORKGROUP);
}
__device__ __forceinline__ void wg_add_f(float* p, float v) {
    __hip_atomic_fetch_add(p, v, __ATOMIC_RELAXED, __HIP_MEMORY_SCOPE_WORKGROUP);
}

__global__ __launch_bounds__(BLK) void edge_pass1(
    const int* __restrict__ srcA, const int* __restrict__ dstA,
    const float* __restrict__ attr, const float* __restrict__ x,
    double2* __restrict__ pk, int* __restrict__ tickets,
    int E, int nchunk, int sliceSz, int N)
{
    const int xcc = xcd_id();
    const int lo  = xcc * sliceSz;
    const int w   = min(sliceSz, N - lo);
    __shared__ int s_q;
    for (;;) {
        if (threadIdx.x == 0) s_q = atomicAdd(&tickets[xcc], 1);
        __syncthreads();
        const int q = s_q;
        __syncthreads();
        if (q * GRAB >= nchunk) break;
        for (int cc = 0; cc < GRAB; ++cc) {
            const int c = q * GRAB + cc;
            if (c >= nchunk) break;
            const int base = c * CHUNK + threadIdx.x * EPT;
            if (base >= E) continue;
            vi4 sv  = __builtin_nontemporal_load((const vi4*)&srcA[base]);
            vi4 dv  = __builtin_nontemporal_load((const vi4*)&dstA[base]);
            vf4 a01 = __builtin_nontemporal_load((const vf4*)&attr[2 * base]);
            vf4 a23 = __builtin_nontemporal_load((const vf4*)&attr[2 * base + 4]);
            #define P1(S, D, AX, AY)                                                  \
                if ((unsigned)((D) - lo) < (unsigned)w) {                             \
                    float diff = x[S] - x[D];                                         \
                    if ((AX) != 0.0f) wg_add_d(&pk[D].x, (double)(diff/(AX)) + PK);   \
                    if ((AY) != 0.0f) wg_add_d(&pk[D].y, (double)(diff/(AY)) + PK);   \
                }
            P1(sv.x, dv.x, a01.x, a01.y)
            P1(sv.y, dv.y, a01.z, a01.w)
            P1(sv.z, dv.z, a23.x, a23.y)
            P1(sv.w, dv.w, a23.z, a23.w)
            #undef P1
        }
    }
}

__global__ __launch_bounds__(BLK) void node_mid(
    double2* __restrict__ pk, const float* __restrict__ a_x, int N)
{
    float4* f4 = (float4*)pk;
    for (int i = blockIdx.x * BLK + threadIdx.x; i < N; i += gridDim.x * BLK) {
        double2 p = pk[i];
        double c0 = rint(p.x * PKI);
        double c1 = rint(p.y * PKI);
        float  s0 = (float)(p.x - c0 * PK);
        float  s1 = (float)(p.y - c1 * PK);
        float  i0 = 1.0f / (float)fmax(c0, 1.0);
        float  i1 = 1.0f / (float)fmax(c1, 1.0);
        float  a  = a_x[i];
        f4[i] = make_float4(a * s0 * i0, a * s1 * i1, i0, i1);
    }
}

__global__ __launch_bounds__(BLK) void edge_pass2(
    const int* __restrict__ srcA, const int* __restrict__ dstA,
    const float* __restrict__ attr, const float4* __restrict__ tf,
    float* __restrict__ acc2, int* __restrict__ tickets,
    int E, int nchunk, int sliceSz, int N)
{
    const int xcc = xcd_id();
    const int lo  = xcc * sliceSz;
    const int w   = min(sliceSz, N - lo);
    __shared__ int s_q;
    for (;;) {
        if (threadIdx.x == 0) s_q = atomicAdd(&tickets[8 + xcc], 1);
        __syncthreads();
        const int q = s_q;
        __syncthreads();
        if (q * GRAB >= nchunk) break;
        for (int cc = 0; cc < GRAB; ++cc) {
            const int c = q * GRAB + cc;
            if (c >= nchunk) break;
            const int base = c * CHUNK + threadIdx.x * EPT;
            if (base >= E) continue;
            vi4 sv  = __builtin_nontemporal_load((const vi4*)&srcA[base]);
            vi4 dv  = __builtin_nontemporal_load((const vi4*)&dstA[base]);
            vf4 a01 = __builtin_nontemporal_load((const vf4*)&attr[2 * base]);
            vf4 a23 = __builtin_nontemporal_load((const vf4*)&attr[2 * base + 4]);
            #define P2(S, D, AX, AY)                                                  \
                if ((unsigned)((D) - lo) < (unsigned)w) {                             \
                    float4 ts = tf[S], td = tf[D];                                    \
                    float contrib = 0.0f; bool any = false;                           \
                    if ((AX) != 0.0f) { contrib += (ts.x - td.x) / (AX) * td.z; any = true; } \
                    if ((AY) != 0.0f) { contrib += (ts.y - td.y) / (AY) * td.w; any = true; } \
                    if (any) wg_add_f(&acc2[D], contrib);                             \
                }
            P2(sv.x, dv.x, a01.x, a01.y)
            P2(sv.y, dv.y, a01.z, a01.w)
            P2(sv.z, dv.z, a23.x, a23.y)
            P2(sv.w, dv.w, a23.z, a23.w)
            #undef P2
        }
    }
}

__global__ __launch_bounds__(BLK) void node_out(
    const float* __restrict__ acc2, const int* __restrict__ mask,
    float* __restrict__ out, int N)
{
    for (int i = blockIdx.x * BLK + threadIdx.x; i < N; i += gridDim.x * BLK)
        out[i] = (acc2[i] + 1.0f) * (1.0f - (float)mask[i]);
}

// ---------------- launcher ----------------

extern "C" void kernel_launch(void* const* d_in, const int* in_sizes, int n_in,
                              void* d_out, int out_size, void* d_ws, size_t ws_size,
                              hipStream_t stream)
{
    const float* x    = (const float*)d_in[0];
    const float* a_x  = (const float*)d_in[1];
    const int*   eidx = (const int*)d_in[2];
    const float* attr = (const float*)d_in[3];
    const int*   mask = (const int*)d_in[4];
    float* out = (float*)d_out;

    const int N = in_sizes[0];
    const int E = in_sizes[2] / 2;
    const int K = (N + BUCKET - 1) >> K_BSH;

    const size_t need = (size_t)E * 8 + (size_t)N * 14 + 16384;
    const size_t bhist_bytes = (size_t)SB * KMAX * 4;   // 4 MB
    const int span = (((E + SB - 1) / SB) + 3) & ~3;

    if (ws_size >= need && N <= (1 << 20) && K <= KMAX &&
        bhist_bytes <= (size_t)N * 12 && span <= SREC_CAP) {
        char* p = (char*)d_ws;
        int2*     ebuf    = (int2*)p;
        unsigned* tpk     = (unsigned*)(p + (size_t)E * 8);
        float2*   inv2    = (float2*)(p + (size_t)E * 8 + (size_t)N * 4);
        unsigned short* xpk = (unsigned short*)(p + (size_t)E * 8 + (size_t)N * 12);
        int*      counts  = (int*)(p + (size_t)E * 8 + (size_t)N * 14);
        int*      offsets = counts + KMAX;        // K+1 slots
        int*      bhist   = (int*)tpk;            // alias tpk+inv2 (dead till phase1)

        const int* srcA = eidx;
        const int* dstA = eidx + E;

        k_hist<<<SB, HT, 0, stream>>>(dstA, x, bhist, xpk, E, K, span, N);
        k_scanA<<<K, 64, 0, stream>>>(bhist, counts);
        k_scanB<<<1, KMAX, 0, stream>>>(counts, offsets, K);
        k_scatter<<<SB, SB_T, 0, stream>>>(srcA, dstA, attr, bhist, counts,
                                           offsets, ebuf, E, K, span);
        k_phase1<<<K, PT, 0, stream>>>(ebuf, offsets, xpk, x, a_x, tpk, inv2, N);
        k_phase2<<<K, PT, 0, stream>>>(ebuf, offsets, tpk, inv2, mask, out, N);
    } else {
        // proven R5 fallback (20N+64 bytes of ws)
        char* ws = (char*)d_ws;
        double2* pk      = (double2*)(ws);
        float*   acc2    = (float*)(ws + (size_t)16 * N);
        int*     tickets = (int*)(ws + (size_t)20 * N);

        hipMemsetAsync(d_ws, 0, (size_t)20 * N + 64, stream);

        const int sliceSz = (N + 7) / 8;
        const int nchunk  = (E + CHUNK - 1) / CHUNK;
        const int EGRID   = 2048;
        int ngrid = (N + BLK - 1) / BLK;
        const int NGRID   = ngrid < 2048 ? ngrid : 2048;

        edge_pass1<<<EGRID, BLK, 0, stream>>>(
            eidx, eidx + E, attr, x, pk, tickets, E, nchunk, sliceSz, N);
        node_mid<<<NGRID, BLK, 0, stream>>>(pk, a_x, N);
        edge_pass2<<<EGRID, BLK, 0, stream>>>(
            eidx, eidx + E, attr, (const float4*)pk, acc2, tickets,
            E, nchunk, sliceSz, N);
        node_out<<<NGRID, BLK, 0, stream>>>(acc2, mask, out, N);
    }
}